// Round 4
// baseline (746.405 us; speedup 1.0000x reference)
//
#include <hip/hip_runtime.h>
#include <math.h>

#define N_NODES 131072
#define N_DST   16384
#define DEG     16
#define HID     256
#define N_EDGES 262144

typedef __bf16 bf16_8 __attribute__((ext_vector_type(8)));
typedef float  f32_4  __attribute__((ext_vector_type(4)));

__device__ __forceinline__ float gelu_f(float v) {
    return 0.5f * v * (1.0f + erff(v * 0.70710678f));
}
__device__ __forceinline__ f32_4 zero4() {
    f32_4 z; z[0] = 0.f; z[1] = 0.f; z[2] = 0.f; z[3] = 0.f; return z;
}

// async global->LDS, 16B per lane. LDS side must be wave-uniform base + lane*16.
__device__ __forceinline__ void load_lds16(const __bf16* g, __bf16* l) {
    __builtin_amdgcn_global_load_lds(
        (__attribute__((address_space(1))) void*)g,
        (__attribute__((address_space(3))) void*)l, 16, 0, 0);
}

// ---------------- prep: fp32 -> bf16 weights ----------------
__global__ void prep_kernel(__bf16* __restrict__ out,
                            const float* __restrict__ w2,
                            const float* __restrict__ w3,
                            const float* __restrict__ mw1,
                            const float* __restrict__ mw2,
                            const float* __restrict__ mw3) {
    int stride = gridDim.x * blockDim.x;
    for (int i = blockIdx.x * blockDim.x + threadIdx.x; i < 589824; i += stride) {
        float v;
        if      (i <  65536) v = w2[i];
        else if (i < 131072) v = w3[i - 65536];
        else if (i < 393216) v = mw1[i - 131072];
        else if (i < 524288) v = mw2[i - 393216];
        else                 v = mw3[i - 524288];
        out[i] = (__bf16)v;
    }
}

// ---------------- encoder layer 1 (K=3): weights in registers, grid-stride ----
// thread = fixed col-group c8 (8 cols, 24 w + 8 b in VGPRs), loops over nodes.
__global__ __launch_bounds__(256) void enc1_kernel(
    const float* __restrict__ x, const float* __restrict__ w1,
    const float* __restrict__ b1, __bf16* __restrict__ h1) {
    const int c8   = threadIdx.x & 31;
    const int nloc = threadIdx.x >> 5;
    float w[24], bb[8];
    #pragma unroll
    for (int i = 0; i < 6; i++) *(float4*)&w[i * 4] = ((const float4*)w1)[c8 * 6 + i];
    *(float4*)&bb[0] = ((const float4*)b1)[c8 * 2 + 0];
    *(float4*)&bb[4] = ((const float4*)b1)[c8 * 2 + 1];
    for (int n = blockIdx.x * 8 + nloc; n < N_NODES; n += gridDim.x * 8) {
        float x0 = x[n * 3 + 0], x1 = x[n * 3 + 1], x2 = x[n * 3 + 2];
        bf16_8 o;
        #pragma unroll
        for (int j = 0; j < 8; j++) {
            float v = fmaf(x2, w[j * 3 + 2],
                      fmaf(x1, w[j * 3 + 1],
                      fmaf(x0, w[j * 3 + 0], bb[j])));
            o[j] = (__bf16)gelu_f(v);
        }
        *(bf16_8*)&h1[(size_t)n * 256 + c8 * 8] = o;
    }
}

// ---------------- tiled GEMM: C = act(A @ W^T + b) [+fourier] [+pool], optional gather ----
// 256 threads = 4 waves (2x2), block tile 128(M)x256(N), wave tile 64x128, BK=64.
// LDS staged via global_load_lds w/ XOR swizzle: slot(row,kgs) holds kg = kgs^(row&7).
template<int K, bool GATHER, bool GELU, bool POOL, bool FOURIER>
__global__ __launch_bounds__(256, 2) void mgemm(
    const __bf16* __restrict__ Ag, const __bf16* __restrict__ h,
    const int* __restrict__ edges, const __bf16* __restrict__ W,
    const float* __restrict__ bias, __bf16* __restrict__ Cb,
    float* __restrict__ Cf, const float* __restrict__ pos,
    const float* __restrict__ bfour, int NB, int Nfull, int e0)
{
    __shared__ __align__(16) __bf16 sMem[(128 + 256) * 64];  // sA 16KB | sB 32KB
    __shared__ int s_src[128];
    __shared__ int s_dst[128];
    __bf16* sA = sMem;
    __bf16* sB = sMem + 128 * 64;

    const int tid  = threadIdx.x;
    const int mblk = blockIdx.x / NB;
    const int nblk = blockIdx.x % NB;
    const int m0 = mblk * 128, n0 = nblk * 256;
    const int wave = tid >> 6, lane = tid & 63, ln = lane & 15, quad = lane >> 4;
    const int wm = wave >> 1, wn = wave & 1;

    if (GATHER && tid < 128) {
        int e = e0 + m0 + tid;
        s_src[tid] = edges[2 * e + 1];
        s_dst[tid] = edges[2 * e + 0];
    }

    f32_4 acc[4][8];
    #pragma unroll
    for (int i = 0; i < 4; i++)
        #pragma unroll
        for (int j = 0; j < 8; j++) acc[i][j] = zero4();

    for (int kb = 0; kb < K / 64; kb++) {
        __syncthreads();  // previous tile consumed (and s_src visible at kb=0)
        #pragma unroll
        for (int i = 0; i < 4; i++) {
            int idx = i * 256 + tid;
            int row = idx >> 3, kgs = idx & 7;
            int kg  = kgs ^ (row & 7);
            const __bf16* gsrc;
            if (GATHER) {
                int col  = kb * 64 + kg * 8;
                int node = (col < 256) ? s_src[row] : s_dst[row];
                gsrc = h + (size_t)node * HID + (col & 255);
            } else {
                gsrc = Ag + (size_t)(m0 + row) * K + kb * 64 + kg * 8;
            }
            load_lds16(gsrc, &sA[idx * 8]);
        }
        #pragma unroll
        for (int i = 0; i < 8; i++) {
            int idx = i * 256 + tid;
            int row = idx >> 3, kgs = idx & 7;
            int kg  = kgs ^ (row & 7);
            const __bf16* gw = W + (size_t)(n0 + row) * K + kb * 64 + kg * 8;
            load_lds16(gw, &sB[idx * 8]);
        }
        __syncthreads();  // drains vmcnt (DMA) per compiler barrier semantics
        #pragma unroll
        for (int ks = 0; ks < 2; ks++) {
            bf16_8 af[4], bfr[8];
            int kg = ks * 4 + quad;
            #pragma unroll
            for (int mt = 0; mt < 4; mt++) {
                int mr = wm * 64 + mt * 16 + ln;
                af[mt] = *(const bf16_8*)&sA[mr * 64 + (kg ^ (mr & 7)) * 8];
            }
            #pragma unroll
            for (int nt = 0; nt < 8; nt++) {
                int nr = wn * 128 + nt * 16 + ln;
                bfr[nt] = *(const bf16_8*)&sB[nr * 64 + (kg ^ (nr & 7)) * 8];
            }
            #pragma unroll
            for (int mt = 0; mt < 4; mt++)
                #pragma unroll
                for (int nt = 0; nt < 8; nt++)
                    acc[mt][nt] = __builtin_amdgcn_mfma_f32_16x16x32_bf16(af[mt], bfr[nt], acc[mt][nt], 0, 0, 0);
        }
    }

    if (POOL) {
        // each 16-row m-tile is exactly one dst group (DEG=16): in-register mean
        #pragma unroll
        for (int nt = 0; nt < 8; nt++) {
            int col = n0 + wn * 128 + nt * 16 + ln;
            float bb = bias[col];
            #pragma unroll
            for (int mt = 0; mt < 4; mt++) {
                float s = acc[mt][nt][0] + acc[mt][nt][1] + acc[mt][nt][2] + acc[mt][nt][3];
                s += __shfl_xor(s, 16);
                s += __shfl_xor(s, 32);
                if (quad == 0) {
                    int eg  = e0 + m0 + wm * 64 + mt * 16;
                    int dst = edges[2 * eg];
                    Cf[(size_t)dst * HID + col] = s * 0.0625f + bb;
                }
            }
        }
    } else {
        // epilogue: bias [+gelu] [+fourier]; LDS-transpose (two nt-halves) for 16B stores
        const bool iscos = FOURIER && (wn == 0);  // Nfull=256 for FOURIER: cols<128 <=> wn==0
        __bf16* sw = sMem + wave * 4096;          // 64x64 bf16 per wave per half
        float p0[4], p1[4];
        if (FOURIER) {
            #pragma unroll
            for (int mt = 0; mt < 4; mt++) {
                int rowE = m0 + wm * 64 + mt * 16 + quad * 4;
                // preload row pos for r=0..3 lazily below (scalar); just cache base row here
                (void)rowE;
            }
        }
        #pragma unroll
        for (int half = 0; half < 2; half++) {
            __syncthreads();  // K-loop reads done / previous half's reads done
            #pragma unroll
            for (int ntl = 0; ntl < 4; ntl++) {
                int nt  = half * 4 + ntl;
                int col = n0 + wn * 128 + nt * 16 + ln;
                float bb = bias[col];
                float Bc0 = 0.f, Bc1 = 0.f;
                if (FOURIER) {
                    int jm = col & 127;
                    Bc0 = bfour[jm * 2 + 0];
                    Bc1 = bfour[jm * 2 + 1];
                }
                #pragma unroll
                for (int mt = 0; mt < 4; mt++) {
                    #pragma unroll
                    for (int r = 0; r < 4; r++) {
                        int rowL = mt * 16 + quad * 4 + r;
                        float v = acc[mt][nt][r] + bb;
                        if (GELU) v = gelu_f(v);
                        if (FOURIER) {
                            int rowE = m0 + wm * 64 + rowL;
                            float f = 6.2831853071795864f *
                                      fmaf(pos[rowE * 2 + 1], Bc1, pos[rowE * 2 + 0] * Bc0);
                            v += iscos ? __cosf(f) : __sinf(f);
                        }
                        int colL = ntl * 16 + ln;
                        sw[rowL * 64 + ((colL + rowL * 8) & 63)] = (__bf16)v;
                    }
                }
            }
            __syncthreads();
            #pragma unroll
            for (int p = 0; p < 8; p++) {
                int rowL = p * 8 + (lane >> 3);
                int c8 = lane & 7;
                bf16_8 vv = *(const bf16_8*)&sw[rowL * 64 + ((c8 * 8 + rowL * 8) & 63)];
                int rowE = m0 + wm * 64 + rowL;
                *(bf16_8*)&Cb[(size_t)rowE * Nfull + n0 + wn * 128 + half * 64 + c8 * 8] = vv;
            }
        }
    }
}

extern "C" void kernel_launch(void* const* d_in, const int* in_sizes, int n_in,
                              void* d_out, int out_size, void* d_ws, size_t ws_size,
                              hipStream_t stream) {
    const float* x     = (const float*)d_in[0];
    const float* pos   = (const float*)d_in[1];
    const int*   edges = (const int*)d_in[2];
    const float* ip_w1 = (const float*)d_in[4];
    const float* ip_b1 = (const float*)d_in[5];
    const float* ip_w2 = (const float*)d_in[6];
    const float* ip_b2 = (const float*)d_in[7];
    const float* ip_w3 = (const float*)d_in[8];
    const float* ip_b3 = (const float*)d_in[9];
    const float* bfour = (const float*)d_in[10];
    const float* mw1   = (const float*)d_in[11];
    const float* mb1   = (const float*)d_in[12];
    const float* mw2   = (const float*)d_in[13];
    const float* mb2   = (const float*)d_in[14];
    const float* mw3   = (const float*)d_in[15];
    const float* mb3   = (const float*)d_in[16];

    char* ws = (char*)d_ws;
    __bf16* hA = (__bf16*)ws;                                // 64 MB: h1, later final h
    __bf16* hB = hA + (size_t)N_NODES * HID;                 // 64 MB: h2 temp
    size_t off = (size_t)N_NODES * HID * 2 * 2;
    __bf16* wb = (__bf16*)(ws + off);                        // 1.125 MB bf16 weights
    off += (size_t)589824 * 2;
    off = (off + 255) & ~(size_t)255;
    char* scratch = ws + off;
    size_t avail = ws_size > off ? ws_size - off : 0;

    // chunk edges so m1 (eC*512) + m2 (eC*256) bf16 fit in remaining workspace
    int C = 1;
    while (C < 16 && ((size_t)N_EDGES / C) * (512 + 256) * 2 > avail) C <<= 1;
    const int eC  = N_EDGES / C;   // edges per chunk
    const int mbC = eC / 128;      // M-blocks per chunk

    __bf16* w2b  = wb;
    __bf16* w3b  = wb + 65536;
    __bf16* mw1b = wb + 131072;
    __bf16* mw2b = wb + 393216;
    __bf16* mw3b = wb + 524288;
    __bf16* m1c  = (__bf16*)scratch;
    __bf16* m2c  = m1c + (size_t)eC * 512;

    prep_kernel<<<2304, 256, 0, stream>>>(wb, ip_w2, ip_w3, mw1, mw2, mw3);

    // encoder: h1 -> hA; h2 = gelu(h1 W2^T+b2) -> hB; h = h2 W3^T+b3+fourier -> hA
    enc1_kernel<<<2048, 256, 0, stream>>>(x, ip_w1, ip_b1, hA);
    mgemm<256, false, true,  false, false><<<1024, 256, 0, stream>>>(
        hA, nullptr, nullptr, w2b, ip_b2, hB, nullptr, nullptr, nullptr, 1, 256, 0);
    mgemm<256, false, false, false, true ><<<1024, 256, 0, stream>>>(
        hB, nullptr, nullptr, w3b, ip_b3, hA, nullptr, pos, bfour, 1, 256, 0);

    for (int c = 0; c < C; c++) {
        int e0 = c * eC;
        mgemm<512, true,  true,  false, false><<<mbC * 2, 256, 0, stream>>>(
            nullptr, hA, edges, mw1b, mb1, m1c, nullptr, nullptr, nullptr, 2, 512, e0);
        mgemm<512, false, true,  false, false><<<mbC, 256, 0, stream>>>(
            m1c, nullptr, edges, mw2b, mb2, m2c, nullptr, nullptr, nullptr, 1, 256, e0);
        mgemm<256, false, false, true,  false><<<mbC, 256, 0, stream>>>(
            m2c, nullptr, edges, mw3b, mb3, nullptr, (float*)d_out, nullptr, nullptr, 1, 256, e0);
    }
}